// Round 1
// baseline (729.902 us; speedup 1.0000x reference)
//
#include <hip/hip_runtime.h>
#include <math.h>

#define T_TOK 8192
#define DM 1024
#define DF 2048
#define NE 16
#define TK 2
#define CAP 1280

typedef __bf16 bf16x8 __attribute__((ext_vector_type(8)));
typedef float f32x4 __attribute__((ext_vector_type(4)));

__device__ __forceinline__ unsigned short f2bf(float f) {
  unsigned int u = __float_as_uint(f);
  unsigned int r = (u + 0x7fffu + ((u >> 16) & 1u)) >> 16;
  return (unsigned short)r;
}

__device__ __forceinline__ void async_copy16(const void* g, void* l) {
  __builtin_amdgcn_global_load_lds(
      (const __attribute__((address_space(1))) void*)g,
      (__attribute__((address_space(3))) void*)l, 16, 0, 0);
}

// ---------------- transpose + fp32->bf16 convert: in (R x Cc) -> out (Cc x R), per expert z
__global__ __launch_bounds__(256) void transpose_conv_kernel(
    const float* __restrict__ in, unsigned short* __restrict__ out, int R, int Cc) {
  __shared__ float tl[32][33];
  size_t eoff = (size_t)blockIdx.z * R * Cc;
  in += eoff; out += eoff;
  int c0 = blockIdx.x * 32, r0 = blockIdx.y * 32;
  int tx = threadIdx.x, ty = threadIdx.y;
#pragma unroll
  for (int r = 0; r < 4; r++)
    tl[ty + r * 8][tx] = in[(size_t)(r0 + ty + r * 8) * Cc + c0 + tx];
  __syncthreads();
#pragma unroll
  for (int r = 0; r < 4; r++)
    out[(size_t)(c0 + ty + r * 8) * R + r0 + tx] = f2bf(tl[tx][ty + r * 8]);
}

// ---------------- gating: one wave per token; sigmoid + top-2 (lowest-index tie-break)
__global__ __launch_bounds__(64) void gate_kernel(
    const float* __restrict__ x, const float* __restrict__ gw,
    int* __restrict__ sel, float* __restrict__ wts) {
  int t = blockIdx.x;
  int lane = threadIdx.x;
  const float* xr = x + (size_t)t * DM;
  float acc[NE];
#pragma unroll
  for (int e = 0; e < NE; e++) acc[e] = 0.f;
  for (int j = 0; j < DM / 64; j++) {
    float xv = xr[j * 64 + lane];
#pragma unroll
    for (int e = 0; e < NE; e++) acc[e] += xv * gw[e * DM + j * 64 + lane];
  }
#pragma unroll
  for (int e = 0; e < NE; e++) {
    float v = acc[e];
#pragma unroll
    for (int off = 32; off > 0; off >>= 1) v += __shfl_xor(v, off);
    acc[e] = v;
  }
  if (lane == 0) {
    float p[NE];
#pragma unroll
    for (int e = 0; e < NE; e++) p[e] = 1.f / (1.f + expf(-acc[e]));
    int i0 = 0;
#pragma unroll
    for (int e = 1; e < NE; e++) if (p[e] > p[i0]) i0 = e;
    int i1 = (i0 == 0) ? 1 : 0;
#pragma unroll
    for (int e = 0; e < NE; e++) if (e != i0 && p[e] > p[i1]) i1 = e;
    float v0 = p[i0], v1 = p[i1], s = v0 + v1 + 1e-6f;
    sel[2 * t] = i0; sel[2 * t + 1] = i1;
    wts[2 * t] = v0 / s; wts[2 * t + 1] = v1 / s;
  }
}

// ---------------- deterministic rank/capacity scan: one block per expert, token-major order
__global__ __launch_bounds__(256) void scan_kernel(
    const int* __restrict__ sel, int* __restrict__ pos_slot,
    int* __restrict__ exp_tok, int* __restrict__ counts) {
  int e = blockIdx.x;
  __shared__ int wsum[4];
  int tid = threadIdx.x, lane = tid & 63, wv = tid >> 6;
  int base = 0;
  for (int p0 = 0; p0 < T_TOK * TK; p0 += 256) {
    int p = p0 + tid;
    int flag = (sel[p] == e) ? 1 : 0;
    unsigned long long b = __ballot(flag);
    int pre = __popcll(b & ((1ull << lane) - 1ull));
    if (lane == 0) wsum[wv] = __popcll(b);
    __syncthreads();
    int wbase = 0;
#pragma unroll
    for (int i = 0; i < 4; i++) if (i < wv) wbase += wsum[i];
    int tot = wsum[0] + wsum[1] + wsum[2] + wsum[3];
    if (flag) {
      int rank = base + wbase + pre;
      if (rank < CAP) {
        pos_slot[p] = e * CAP + rank;
        exp_tok[e * CAP + rank] = p;
      } else {
        pos_slot[p] = -1;
      }
    }
    base += tot;
    __syncthreads();
  }
  if (tid == 0) counts[e] = base < CAP ? base : CAP;
}

// ---------------- gather tokens into padded [E,CAP,DM] bf16 (zero-fill past count)
__global__ __launch_bounds__(128) void gather_kernel(
    const float* __restrict__ x, const int* __restrict__ exp_tok,
    const int* __restrict__ counts, unsigned short* __restrict__ Xp) {
  int i = blockIdx.x, e = blockIdx.y;
  int tid = threadIdx.x;
  unsigned short* dst = Xp + ((size_t)e * CAP + i) * DM;
  int4 pk = make_int4(0, 0, 0, 0);
  if (i < counts[e]) {
    int p = exp_tok[e * CAP + i];
    int t = p >> 1;
    const float4* src = (const float4*)(x + (size_t)t * DM);
    float4 v0 = src[tid * 2];
    float4 v1 = src[tid * 2 + 1];
    union { unsigned short u[8]; int4 v; } q;
    q.u[0] = f2bf(v0.x); q.u[1] = f2bf(v0.y); q.u[2] = f2bf(v0.z); q.u[3] = f2bf(v0.w);
    q.u[4] = f2bf(v1.x); q.u[5] = f2bf(v1.y); q.u[6] = f2bf(v1.z); q.u[7] = f2bf(v1.w);
    pk = q.v;
  }
  ((int4*)dst)[tid] = pk;
}

// ---------------- bf16 MFMA GEMM, m97 structure: A [M,K] row-major, Bt [N,K] row-major
__device__ __forceinline__ void storev(unsigned short* p, float v) { *p = f2bf(v); }
__device__ __forceinline__ void storev(float* p, float v) { *p = v; }

template <bool GELU, typename OutT>
__global__ __launch_bounds__(256) void gemm_bt_kernel(
    const unsigned short* __restrict__ A, const unsigned short* __restrict__ Bt,
    OutT* __restrict__ C, int M, int N, int K,
    size_t sA, size_t sB, size_t sC) {
  __shared__ unsigned short As[128 * 32];
  __shared__ unsigned short Bs[128 * 32];
  A += (size_t)blockIdx.z * sA;
  Bt += (size_t)blockIdx.z * sB;
  C += (size_t)blockIdx.z * sC;
  int m0 = blockIdx.y * 128, n0 = blockIdx.x * 128;
  int tid = threadIdx.x;
  int lane = tid & 63;
  int wv = tid >> 6;
  int wm = (wv >> 1) * 64, wn = (wv & 1) * 64;
  int qd = lane >> 4, lm = lane & 15;

  const unsigned short* a0 = A + (size_t)(m0 + (tid >> 2)) * K + (tid & 3) * 8;
  const unsigned short* a1 = a0 + (size_t)64 * K;
  const unsigned short* b0 = Bt + (size_t)(n0 + (tid >> 2)) * K + (tid & 3) * 8;
  const unsigned short* b1 = b0 + (size_t)64 * K;
  char* lAs = (char*)As;
  char* lBs = (char*)Bs;

  f32x4 acc[4][4] = {};
  for (int k0 = 0; k0 < K; k0 += 32) {
    __syncthreads();
    async_copy16(a0 + k0, lAs + tid * 16);
    async_copy16(a1 + k0, lAs + (tid + 256) * 16);
    async_copy16(b0 + k0, lBs + tid * 16);
    async_copy16(b1 + k0, lBs + (tid + 256) * 16);
    __syncthreads();
    bf16x8 af[4], bfr[4];
#pragma unroll
    for (int i = 0; i < 4; i++)
      af[i] = *(const bf16x8*)(lAs + (wm + i * 16 + lm) * 64 + qd * 16);
#pragma unroll
    for (int j = 0; j < 4; j++)
      bfr[j] = *(const bf16x8*)(lBs + (wn + j * 16 + lm) * 64 + qd * 16);
#pragma unroll
    for (int i = 0; i < 4; i++)
#pragma unroll
      for (int j = 0; j < 4; j++)
        acc[i][j] = __builtin_amdgcn_mfma_f32_16x16x32_bf16(af[i], bfr[j], acc[i][j], 0, 0, 0);
  }
#pragma unroll
  for (int i = 0; i < 4; i++) {
    int row = m0 + wm + i * 16 + qd * 4;
#pragma unroll
    for (int j = 0; j < 4; j++) {
      int col = n0 + wn + j * 16 + lm;
#pragma unroll
      for (int r = 0; r < 4; r++) {
        float v = acc[i][j][r];
        if (GELU) v = 0.5f * v * (1.f + erff(v * 0.70710678118f));
        storev(&C[(size_t)(row + r) * N + col], v);
      }
    }
  }
}

// ---------------- weighted combine back to token order (fp32 out)
__global__ __launch_bounds__(128) void combine_kernel(
    const float* __restrict__ outp, const int* __restrict__ pos_slot,
    const float* __restrict__ wts, float* __restrict__ out) {
  int t = blockIdx.x, tid = threadIdx.x;
  float4 r0 = make_float4(0.f, 0.f, 0.f, 0.f);
  float4 r1 = make_float4(0.f, 0.f, 0.f, 0.f);
#pragma unroll
  for (int k = 0; k < 2; k++) {
    int p = 2 * t + k;
    int s = pos_slot[p];
    if (s >= 0) {
      float w = wts[p];
      const float4* src = (const float4*)(outp + (size_t)s * DM);
      float4 a = src[tid * 2], b = src[tid * 2 + 1];
      r0.x += w * a.x; r0.y += w * a.y; r0.z += w * a.z; r0.w += w * a.w;
      r1.x += w * b.x; r1.y += w * b.y; r1.z += w * b.z; r1.w += w * b.w;
    }
  }
  float4* dst = (float4*)(out + (size_t)t * DM);
  dst[tid * 2] = r0;
  dst[tid * 2 + 1] = r1;
}

extern "C" void kernel_launch(void* const* d_in, const int* in_sizes, int n_in,
                              void* d_out, int out_size, void* d_ws, size_t ws_size,
                              hipStream_t stream) {
  (void)in_sizes; (void)n_in; (void)out_size; (void)ws_size;
  const float* x  = (const float*)d_in[0];
  const float* gw = (const float*)d_in[1];
  const float* w1 = (const float*)d_in[2];
  const float* w2 = (const float*)d_in[3];
  float* out = (float*)d_out;

  char* ws = (char*)d_ws;
  unsigned short* w1t = (unsigned short*)ws; ws += (size_t)NE * DM * DF * 2;
  unsigned short* w2t = (unsigned short*)ws; ws += (size_t)NE * DF * DM * 2;
  unsigned short* Xp  = (unsigned short*)ws; ws += (size_t)NE * CAP * DM * 2;
  unsigned short* H   = (unsigned short*)ws; ws += (size_t)NE * CAP * DF * 2;
  float* outp = (float*)ws;  ws += (size_t)NE * CAP * DM * 4;
  int* sel = (int*)ws;       ws += (size_t)T_TOK * TK * 4;
  float* wts = (float*)ws;   ws += (size_t)T_TOK * TK * 4;
  int* pos_slot = (int*)ws;  ws += (size_t)T_TOK * TK * 4;
  int* exp_tok = (int*)ws;   ws += (size_t)NE * CAP * 4;
  int* counts = (int*)ws;    ws += (size_t)NE * 4;

  // weights: fp32 -> bf16, transposed to [N,K] per expert
  transpose_conv_kernel<<<dim3(DF / 32, DM / 32, NE), dim3(32, 8), 0, stream>>>(w1, w1t, DM, DF);
  transpose_conv_kernel<<<dim3(DM / 32, DF / 32, NE), dim3(32, 8), 0, stream>>>(w2, w2t, DF, DM);
  // routing
  gate_kernel<<<T_TOK, 64, 0, stream>>>(x, gw, sel, wts);
  scan_kernel<<<NE, 256, 0, stream>>>(sel, pos_slot, exp_tok, counts);
  gather_kernel<<<dim3(CAP, NE), 128, 0, stream>>>(x, exp_tok, counts, Xp);
  // expert FFN
  gemm_bt_kernel<true, unsigned short><<<dim3(DF / 128, CAP / 128, NE), 256, 0, stream>>>(
      Xp, w1t, H, CAP, DF, DM, (size_t)CAP * DM, (size_t)DM * DF, (size_t)CAP * DF);
  gemm_bt_kernel<false, float><<<dim3(DM / 128, CAP / 128, NE), 256, 0, stream>>>(
      H, w2t, outp, CAP, DM, DF, (size_t)CAP * DF, (size_t)DF * DM, (size_t)CAP * DM);
  // un-permute + weighted sum
  combine_kernel<<<T_TOK, 128, 0, stream>>>(outp, pos_slot, wts, out);
}